// Round 7
// baseline (10.169 us; speedup 1.0000x reference)
//
#include <hip/hip_runtime.h>
#include <math.h>

// MBR area, 8 lanes/sample. Lane k owns pivot k (rotated load: slot l <-
// original point (l+k)&7, so the pivot is slot 0 and all register indexing is
// compile-time). For a CCW convex hull each pivot has AT MOST ONE outgoing
// hull edge, so the lane picks its first passing j via predicated selects and
// does one rotate/min-max block in-place; 3-step shfl_xor min-reduce.
//
// Edge test: 21 unique crosses per pivot; mirrored pair tested as +-(same c),
// matching the reference's exact-negation symmetry. The exactly-zero
// l==pivot / l==j crosses are skipped at compile time (they always pass in
// the reference). FMA contraction on the generic crosses is safe: a sign flip
// needs |c| ~ ulp (near-collinear triple), where the neighboring passing edge
// yields an epsilon-identical box area (tolerance 0.655, we sit at ~0.06).
//
// Rotation identity: reference's (cos,sin) after |fmod(atan2,pi/2)| folding
// equals (|dx|,|dy|)/L if dx>=0 else (|dy|,|dx|)/L. We use unnormalized
// (a,b) = L*(cos,sin) and divide the area by L^2 = dx^2+dy^2 once (rcp).
//
// Min/max reductions are written as nested-triple trees so clang can fuse
// v_min3/v_max3_f32 (min/max reassociation is exact: result is an input).

__global__ __launch_bounds__(256)
void mbr_area_kernel(const float* __restrict__ corners,
                     float* __restrict__ out, int n) {
    int t = blockIdx.x * blockDim.x + threadIdx.x;
    int s = t >> 3;   // sample
    int k = t & 7;    // this lane's pivot (original index)
    if (s >= n) return;

    // Rotated load: slot l holds original point (l+k)&7 (pivot in slot 0).
    const float2* pts = (const float2*)(corners + (size_t)s * 16);
    float px[8], py[8];
#pragma unroll
    for (int l = 0; l < 8; ++l) {
        float2 v = pts[(l + k) & 7];
        px[l] = v.x; py[l] = v.y;
    }

    // Deltas relative to the pivot.
    float qx[8], qy[8];
#pragma unroll
    for (int l = 1; l < 8; ++l) {
        qx[l] = px[l] - px[0];
        qy[l] = py[l] - py[0];
    }

    // Edge bits from the 21 unique crosses. bool-AND -> v_cmp + s_and_b64
    // (scalar pipe), cheaper than float-min accumulation.
    bool edge[8];
#pragma unroll
    for (int j = 1; j < 8; ++j) edge[j] = true;
#pragma unroll
    for (int j = 1; j < 8; ++j) {
#pragma unroll
        for (int l = j + 1; l < 8; ++l) {
            float c = qx[j] * qy[l] - qy[j] * qx[l];  // contraction OK (header)
            edge[j] = edge[j] && (c >= 0.0f);   // point l vs edge (0->j)
            edge[l] = edge[l] && (c <= 0.0f);   // exact mirror for (0->l)
        }
    }

    // First passing j (unique in general position; exact-collinear dups share
    // the direction -> same area).
    float bdx = 0.0f, bdy = 0.0f;
    bool found = false;
#pragma unroll
    for (int j = 1; j < 8; ++j) {
        bool take = edge[j] && !found;
        bdx = take ? qx[j] : bdx;
        bdy = take ? qy[j] : bdy;
        found = found || edge[j];
    }

    // One rotate block for this lane's edge (if any).
    float a0 = fabsf(bdx), b0 = fabsf(bdy);
    float a = (bdx >= 0.0f) ? a0 : b0;
    float b = (bdx >= 0.0f) ? b0 : a0;

    float u[8], v[8];
#pragma unroll
    for (int l = 0; l < 8; ++l) {
        u[l] = a * px[l] + b * py[l];   //  cos*x + sin*y  (scaled by L)
        v[l] = a * py[l] - b * px[l];   // -sin*x + cos*y  (scaled by L)
    }
    float uA = fmaxf(fmaxf(u[0], u[1]), u[2]);
    float uB = fmaxf(fmaxf(u[3], u[4]), u[5]);
    float umax = fmaxf(fmaxf(uA, uB), fmaxf(u[6], u[7]));
    float ua = fminf(fminf(u[0], u[1]), u[2]);
    float ub = fminf(fminf(u[3], u[4]), u[5]);
    float umin = fminf(fminf(ua, ub), fminf(u[6], u[7]));
    float vA = fmaxf(fmaxf(v[0], v[1]), v[2]);
    float vB = fmaxf(fmaxf(v[3], v[4]), v[5]);
    float vmax = fmaxf(fmaxf(vA, vB), fmaxf(v[6], v[7]));
    float va = fminf(fminf(v[0], v[1]), v[2]);
    float vb = fminf(fminf(v[3], v[4]), v[5]);
    float vmin = fminf(fminf(va, vb), fminf(v[6], v[7]));

    float inv = __builtin_amdgcn_rcpf(bdx * bdx + bdy * bdy);
    float area = (umax - umin) * (vmax - vmin) * inv;
    float best = found ? area : INFINITY;

    // Min-reduce across the 8-lane group (aligned within the wave).
    best = fminf(best, __shfl_xor(best, 1));
    best = fminf(best, __shfl_xor(best, 2));
    best = fminf(best, __shfl_xor(best, 4));
    if (k == 0) out[s] = best;
}

extern "C" void kernel_launch(void* const* d_in, const int* in_sizes, int n_in,
                              void* d_out, int out_size, void* d_ws, size_t ws_size,
                              hipStream_t stream) {
    const float* corners = (const float*)d_in[0];
    float* out = (float*)d_out;
    int n = in_sizes[0] / 16;   // K*2 = 16 floats per sample
    int threads = 256;
    long long total = (long long)n * 8;
    int blocks = (int)((total + threads - 1) / threads);
    mbr_area_kernel<<<blocks, threads, 0, stream>>>(corners, out, n);
}